// Round 7
// baseline (171.302 us; speedup 1.0000x reference)
//
#include <hip/hip_runtime.h>
#include <hip/hip_bf16.h>

typedef unsigned short ushort_t;
typedef __attribute__((ext_vector_type(8))) short short8;
typedef __attribute__((ext_vector_type(8))) unsigned short u16x8;
typedef __attribute__((ext_vector_type(4))) float f32x4;

#define BETA 0.4f
#define EPS_C 0.05f
#define NB 8192
#define NH 1024
#define NL 2048
#define NC 5

static __device__ __forceinline__ float b2f(unsigned short u) {
    union { unsigned int i; float f; } x; x.i = ((unsigned int)u) << 16; return x.f;
}
static __device__ __forceinline__ unsigned short f2b(float f) {
    union { float f; unsigned int i; } x; x.f = f;
    unsigned int i = x.i;
    unsigned int r = (i + 0x7FFFu + ((i >> 16) & 1u)) >> 16;
    return (unsigned short)r;
}

static __device__ __forceinline__ void gload16(const ushort_t* g, ushort_t* l) {
    __builtin_amdgcn_global_load_lds((const __attribute__((address_space(1))) void*)g,
                                     (__attribute__((address_space(3))) void*)l, 16, 0, 0);
}

#define CFENCE() asm volatile("" ::: "memory")
#define MFMA16(d, a, b) __builtin_amdgcn_mfma_f32_16x16x32_bf16(a, b, d, 0, 0, 0)

// ---------------- conversion kernels ----------------
__global__ __launch_bounds__(256) void cvt_kernel(const float* __restrict__ in,
                                                  ushort_t* __restrict__ out, long n) {
    long i = ((long)blockIdx.x * 256 + threadIdx.x) * 8;
    if (i >= n) return;
    const float4 a = *(const float4*)(in + i);
    const float4 b = *(const float4*)(in + i + 4);
    u16x8 o;
    o[0] = f2b(a.x); o[1] = f2b(a.y); o[2] = f2b(a.z); o[3] = f2b(a.w);
    o[4] = f2b(b.x); o[5] = f2b(b.y); o[6] = f2b(b.z); o[7] = f2b(b.w);
    *(u16x8*)(out + i) = o;
}

// W1 [2048,1024] -> W1T bf16 [1024,2048]
__global__ __launch_bounds__(256) void trans_kernel(const float* __restrict__ W1,
                                                    ushort_t* __restrict__ W1Tb) {
    __shared__ float tile[32][33];
    const int tx = threadIdx.x & 31, ty = threadIdx.x >> 5;
    const int k0 = blockIdx.x * 32, n0 = blockIdx.y * 32;
#pragma unroll
    for (int i = 0; i < 4; ++i)
        tile[ty + i * 8][tx] = W1[(size_t)(k0 + ty + i * 8) * NH + n0 + tx];
    __syncthreads();
#pragma unroll
    for (int i = 0; i < 4; ++i)
        W1Tb[(size_t)(n0 + ty + i * 8) * NL + k0 + tx] = f2b(tile[tx][ty + i * 8]);
}

// ============ GEMM1: split-K-in-block, stage-early/wait-late, 1 barrier/tile ============
// A=x [8192,2048], Bt=W1T [1024,2048]; tile 256x128, BK=64, 32 K-tiles.
// 8 waves = 2M x 2N x 2Ksl; wave = 128 rows x 64 cols x 32k. Epilogue: pair-reduce + tanh.
__global__ __launch_bounds__(512, 2) void gemm1_sk(const ushort_t* __restrict__ A,
                                                   const ushort_t* __restrict__ Bt,
                                                   const float* __restrict__ b1,
                                                   ushort_t* __restrict__ hout) {
    __shared__ ushort_t As[2][16384];   // 256 x 64, 128B rows, XOR-swz 16B slots (64KB)
    __shared__ ushort_t Bs[2][8192];    // 128 x 64 (32KB)

    const int tid = threadIdx.x;
    const int wv = tid >> 6, lane = tid & 63;
    const int wm = (wv >> 2) & 1, wn = (wv >> 1) & 1, ws = wv & 1;
    const int fr = lane & 15, fg = lane >> 4;
    const int xcd = blockIdx.x & 7, loc = blockIdx.x >> 3;
    const int bm0 = (xcd * 4 + (loc >> 3)) * 256;
    const int bnIdx = loc & 7;
    const int bn0 = bnIdx * 128;
    const int srow = lane >> 3, scol = ((lane & 7) ^ srow) << 3;

#define G1_STA(BUF, KT) {                                                   \
    _Pragma("unroll") for (int c_ = 0; c_ < 4; ++c_) {                      \
        const int rb_ = (c_ * 8 + wv) * 8 + srow;                           \
        gload16(A + (size_t)(bm0 + rb_) * 2048 + (KT) * 64 + scol,          \
                &As[BUF][(c_ * 8 + wv) * 512]);                             \
    } }
#define G1_STB(BUF, KT) {                                                   \
    _Pragma("unroll") for (int c_ = 0; c_ < 2; ++c_) {                      \
        const int rb_ = (c_ * 8 + wv) * 8 + srow;                           \
        gload16(Bt + (size_t)(bn0 + rb_) * 2048 + (KT) * 64 + scol,         \
                &Bs[BUF][(c_ * 8 + wv) * 512]);                             \
    } }

    auto ldA = [&](int buf, int mf) -> short8 {
        const int row = wm * 128 + mf * 16 + fr;
        const int slot = ((ws << 2) + fg) ^ (row & 7);
        return *(const short8*)&As[buf][row * 64 + slot * 8];
    };
    auto ldB = [&](int buf, int nf) -> short8 {
        const int row = wn * 64 + nf * 16 + fr;
        const int slot = ((ws << 2) + fg) ^ (row & 7);
        return *(const short8*)&Bs[buf][row * 64 + slot * 8];
    };

    f32x4 acc[8][4] = {};

    // prologue: stage tile 0 into buf0 (first tile's vmcnt drains it)
    G1_STA(0, 0) G1_STB(0, 0)

#define G1_TILE(BUF, TT) {                                                  \
    const int t_ = (TT);                                                    \
    asm volatile("s_waitcnt vmcnt(0)" ::: "memory");                        \
    CFENCE(); __builtin_amdgcn_s_barrier(); CFENCE();                       \
    if (t_ + 1 < 32) { G1_STA(BUF ^ 1, t_ + 1) G1_STB(BUF ^ 1, t_ + 1) }    \
    short8 af[8], bf[4];                                                    \
    _Pragma("unroll") for (int m = 0; m < 8; ++m) af[m] = ldA(BUF, m);      \
    _Pragma("unroll") for (int n = 0; n < 4; ++n) bf[n] = ldB(BUF, n);      \
    __builtin_amdgcn_s_setprio(1);                                          \
    _Pragma("unroll") for (int m = 0; m < 8; ++m)                           \
        _Pragma("unroll") for (int n = 0; n < 4; ++n)                       \
            acc[m][n] = MFMA16(acc[m][n], af[m], bf[n]);                    \
    __builtin_amdgcn_s_setprio(0);                                          \
    }

#pragma unroll 1
    for (int t = 0; t < 32; t += 2) {
        G1_TILE(0, t)
        G1_TILE(1, t + 1)
    }
#undef G1_TILE
#undef G1_STA
#undef G1_STB

    // epilogue: ws=1 partner writes partials to LDS; ws=0 adds, tanh, stores.
    float* red = (float*)&As[0][0];   // 16384 floats = 64KB (2 regions of 32KB by wn)
#pragma unroll 1
    for (int rd = 0; rd < 2; ++rd) {
        __syncthreads();
        if (ws == 1 && wm == rd) {
#pragma unroll
            for (int m = 0; m < 8; ++m)
#pragma unroll
                for (int n = 0; n < 4; ++n)
#pragma unroll
                    for (int r = 0; r < 4; ++r)
                        red[wn * 8192 + (m * 16 + fg * 4 + r) * 64 + n * 16 + fr] =
                            acc[m][n][r];
        }
        __syncthreads();
        if (ws == 0 && wm == rd) {
#pragma unroll
            for (int m = 0; m < 8; ++m)
#pragma unroll
                for (int n = 0; n < 4; ++n) {
                    const int col = bn0 + wn * 64 + n * 16 + fr;
                    const float bb = b1[col];
#pragma unroll
                    for (int r = 0; r < 4; ++r) {
                        const float s = acc[m][n][r] +
                            red[wn * 8192 + (m * 16 + fg * 4 + r) * 64 + n * 16 + fr];
                        const int row = bm0 + wm * 128 + m * 16 + fg * 4 + r;
                        hout[(size_t)row * NH + col] = f2b(tanhf(s + bb));
                    }
                }
        }
    }
}

// ============ GEMM2: same template, 256x256, no split-K ============
// A=v [8192,1024], Bt=W1b [2048,1024]; tile 256x256, BK=64, 16 K-tiles.
// 8 waves = 2M x 4N; wave = 128 x 64, 2 k-substeps. Epilogue: row |.| partials.
__global__ __launch_bounds__(512, 2) void gemm2_v3(const ushort_t* __restrict__ A,
                                                   const ushort_t* __restrict__ Bt,
                                                   float* __restrict__ partout) {
    __shared__ ushort_t As[2][16384];   // 256 x 64 (64KB)
    __shared__ ushort_t Bs[2][16384];   // 256 x 64 (64KB)

    const int tid = threadIdx.x;
    const int wv = tid >> 6, lane = tid & 63;
    const int wm = wv >> 2, wn = wv & 3;
    const int fr = lane & 15, fg = lane >> 4;
    const int xcd = blockIdx.x & 7, loc = blockIdx.x >> 3;
    const int bm0 = (xcd * 4 + (loc >> 3)) * 256;
    const int bnIdx = loc & 7;
    const int bn0 = bnIdx * 256;
    const int srow = lane >> 3, scol = ((lane & 7) ^ srow) << 3;

#define G2_STA(BUF, KT) {                                                   \
    _Pragma("unroll") for (int c_ = 0; c_ < 4; ++c_) {                      \
        const int rb_ = (c_ * 8 + wv) * 8 + srow;                           \
        gload16(A + (size_t)(bm0 + rb_) * 1024 + (KT) * 64 + scol,          \
                &As[BUF][(c_ * 8 + wv) * 512]);                             \
    } }
#define G2_STB(BUF, KT) {                                                   \
    _Pragma("unroll") for (int c_ = 0; c_ < 4; ++c_) {                      \
        const int rb_ = (c_ * 8 + wv) * 8 + srow;                           \
        gload16(Bt + (size_t)(bn0 + rb_) * 1024 + (KT) * 64 + scol,         \
                &Bs[BUF][(c_ * 8 + wv) * 512]);                             \
    } }

    auto ldA = [&](int buf, int mf, int ks) -> short8 {
        const int row = wm * 128 + mf * 16 + fr;
        const int slot = ((ks << 2) + fg) ^ (row & 7);
        return *(const short8*)&As[buf][row * 64 + slot * 8];
    };
    auto ldB = [&](int buf, int nf, int ks) -> short8 {
        const int row = wn * 64 + nf * 16 + fr;
        const int slot = ((ks << 2) + fg) ^ (row & 7);
        return *(const short8*)&Bs[buf][row * 64 + slot * 8];
    };

    f32x4 acc[8][4] = {};

    G2_STA(0, 0) G2_STB(0, 0)

#define G2_TILE(BUF, TT) {                                                  \
    const int t_ = (TT);                                                    \
    asm volatile("s_waitcnt vmcnt(0)" ::: "memory");                        \
    CFENCE(); __builtin_amdgcn_s_barrier(); CFENCE();                       \
    if (t_ + 1 < 16) { G2_STA(BUF ^ 1, t_ + 1) G2_STB(BUF ^ 1, t_ + 1) }    \
    short8 af[8], bf[4];                                                    \
    _Pragma("unroll") for (int m = 0; m < 8; ++m) af[m] = ldA(BUF, m, 0);   \
    _Pragma("unroll") for (int n = 0; n < 4; ++n) bf[n] = ldB(BUF, n, 0);   \
    __builtin_amdgcn_s_setprio(1);                                          \
    _Pragma("unroll") for (int m = 0; m < 8; ++m)                           \
        _Pragma("unroll") for (int n = 0; n < 4; ++n)                       \
            acc[m][n] = MFMA16(acc[m][n], af[m], bf[n]);                    \
    __builtin_amdgcn_s_setprio(0);                                          \
    _Pragma("unroll") for (int m = 0; m < 8; ++m) af[m] = ldA(BUF, m, 1);   \
    _Pragma("unroll") for (int n = 0; n < 4; ++n) bf[n] = ldB(BUF, n, 1);   \
    __builtin_amdgcn_s_setprio(1);                                          \
    _Pragma("unroll") for (int m = 0; m < 8; ++m)                           \
        _Pragma("unroll") for (int n = 0; n < 4; ++n)                       \
            acc[m][n] = MFMA16(acc[m][n], af[m], bf[n]);                    \
    __builtin_amdgcn_s_setprio(0);                                          \
    }

#pragma unroll 1
    for (int t = 0; t < 16; t += 2) {
        G2_TILE(0, t)
        G2_TILE(1, t + 1)
    }
#undef G2_TILE
#undef G2_STA
#undef G2_STB

    // epilogue: per-row |.| partial sums
    __syncthreads();
    float* rsum = (float*)&As[0][0];
#pragma unroll
    for (int m = 0; m < 8; ++m)
#pragma unroll
        for (int r = 0; r < 4; ++r) {
            float s = 0.f;
#pragma unroll
            for (int n = 0; n < 4; ++n) s += fabsf(acc[m][n][r]);
            s += __shfl_xor(s, 1); s += __shfl_xor(s, 2);
            s += __shfl_xor(s, 4); s += __shfl_xor(s, 8);
            if (fr == 0) rsum[wn * 256 + wm * 128 + m * 16 + fg * 4 + r] = s;
        }
    __syncthreads();
    if (tid < 256)
        partout[(size_t)bnIdx * NB + bm0 + tid] =
            rsum[tid] + rsum[256 + tid] + rsum[512 + tid] + rsum[768 + tid];
}

// ---------------- per-row kernel: logits, losses, v ----------------
__global__ __launch_bounds__(256) void rows_kernel(const ushort_t* __restrict__ hb,
                                                   const int* __restrict__ y,
                                                   const float* __restrict__ W2,
                                                   const float* __restrict__ b2,
                                                   ushort_t* __restrict__ vb,
                                                   float4* __restrict__ rowstats) {
    __shared__ float w2s[NH * NC];
    __shared__ float b2s[NC];
    const int tid = threadIdx.x;
    for (int i = tid; i < NH * NC; i += 256) w2s[i] = W2[i];
    if (tid < NC) b2s[tid] = b2[tid];
    __syncthreads();
    const int wid = tid >> 6, lane = tid & 63;
    const int row = blockIdx.x * 4 + wid;
    const ushort_t* hrow = hb + (size_t)row * NH;
    ushort_t* vrow = vb + (size_t)row * NH;
    const int yi = y[row];
    float d0 = 0, d1 = 0, d2 = 0, d3 = 0, d4 = 0;
#pragma unroll
    for (int it = 0; it < 2; ++it) {
        const int n0 = it * 512 + lane * 8;
        u16x8 hv = *(const u16x8*)(hrow + n0);
        u16x8 ov;
#pragma unroll
        for (int j = 0; j < 8; ++j) {
            float hh = b2f(hv[j]);
            const float* wrow = &w2s[(n0 + j) * NC];
            d0 += hh * wrow[0]; d1 += hh * wrow[1]; d2 += hh * wrow[2];
            d3 += hh * wrow[3]; d4 += hh * wrow[4];
            ov[j] = f2b((1.f - hh * hh) * wrow[yi]);
        }
        *(u16x8*)(vrow + n0) = ov;
    }
#pragma unroll
    for (int off = 32; off; off >>= 1) {
        d0 += __shfl_xor(d0, off); d1 += __shfl_xor(d1, off); d2 += __shfl_xor(d2, off);
        d3 += __shfl_xor(d3, off); d4 += __shfl_xor(d4, off);
    }
    if (lane == 0) {
        float lg[NC] = { d0 + b2s[0], d1 + b2s[1], d2 + b2s[2], d3 + b2s[3], d4 + b2s[4] };
        float zy = lg[yi];
        float mse = 0.f, marg = 0.f;
        int amax = 0; float best = lg[0];
#pragma unroll
        for (int c = 0; c < NC; ++c) {
            float t = lg[c] - (c == yi ? 1.f : 0.f);
            mse += t * t;
            if (c != yi) marg += fmaxf(1.f - zy + lg[c], 0.f);
            if (lg[c] > best) { best = lg[c]; amax = c; }
        }
        rowstats[row] = make_float4(zy, mse, marg, (amax == yi) ? 1.f : 0.f);
    }
}

// ---------------- reductions ----------------
__global__ __launch_bounds__(256) void reduce_rows(const float4* __restrict__ rs,
                                                   const float* __restrict__ part,
                                                   int NT, float4* __restrict__ bsums) {
    const int tid = threadIdx.x;
    const int r = blockIdx.x * 256 + tid;
    float4 v = rs[r];
    float wl1 = 0.f;
    for (int t = 0; t < NT; ++t) wl1 += part[(size_t)t * NB + r];
    float R = wl1 * EPS_C / (fabsf(v.x) + 1e-8f);
    float4 s = make_float4(v.y, v.z, v.w, log1pf(R));
#pragma unroll
    for (int off = 32; off; off >>= 1) {
        s.x += __shfl_down(s.x, off); s.y += __shfl_down(s.y, off);
        s.z += __shfl_down(s.z, off); s.w += __shfl_down(s.w, off);
    }
    __shared__ float4 red[4];
    if ((tid & 63) == 0) red[tid >> 6] = s;
    __syncthreads();
    if (tid == 0) {
        float4 t = red[0];
        for (int i = 1; i < 4; ++i) { t.x += red[i].x; t.y += red[i].y; t.z += red[i].z; t.w += red[i].w; }
        bsums[blockIdx.x] = t;
    }
}

__global__ void final_combine(const float4* __restrict__ bsums, int nb, float* __restrict__ out) {
    const int l = threadIdx.x;
    float4 s = (l < nb) ? bsums[l] : make_float4(0.f, 0.f, 0.f, 0.f);
#pragma unroll
    for (int off = 32; off; off >>= 1) {
        s.x += __shfl_down(s.x, off); s.y += __shfl_down(s.y, off);
        s.z += __shfl_down(s.z, off); s.w += __shfl_down(s.w, off);
    }
    if (l == 0) {
        const float Bf = (float)NB;
        out[0] = s.x / (Bf * (float)NC) + (s.y / Bf + BETA * s.w / Bf) * (s.z / Bf);
    }
}

extern "C" void kernel_launch(void* const* d_in, const int* in_sizes, int n_in,
                              void* d_out, int out_size, void* d_ws, size_t ws_size,
                              hipStream_t stream) {
    const float* x  = (const float*)d_in[0];
    const int*   y  = (const int*)d_in[1];
    const float* W1 = (const float*)d_in[2];
    const float* b1 = (const float*)d_in[3];
    const float* W2 = (const float*)d_in[4];
    const float* b2 = (const float*)d_in[5];
    float* out = (float*)d_out;

    char* ws = (char*)d_ws;
    ushort_t* W1Tb = (ushort_t*)(ws);                           // 4MB
    ushort_t* W1b  = (ushort_t*)(ws + (4ul << 20));             // 4MB
    ushort_t* xb   = (ushort_t*)(ws + (8ul << 20));             // 32MB
    ushort_t* hb   = (ushort_t*)(ws + (40ul << 20));            // 16MB
    ushort_t* vb   = (ushort_t*)(ws + (56ul << 20));            // 16MB
    float4*   rowstats = (float4*)(ws + (72ul << 20));          // 128KB
    float*    part = (float*)(ws + (72ul << 20) + (1ul << 20)); // 256KB
    float4*   bsums = (float4*)(ws + (74ul << 20));             // 512B

    // 1. conversions
    cvt_kernel<<<(NB * (long)NL) / (256 * 8), 256, 0, stream>>>(x, xb, (long)NB * NL);
    cvt_kernel<<<(NL * (long)NH) / (256 * 8), 256, 0, stream>>>(W1, W1b, (long)NL * NH);
    trans_kernel<<<dim3(NL / 32, NH / 32), 256, 0, stream>>>(W1, W1Tb);

    // 2. GEMM1 (split-K-in-block): h = tanh(x @ W1 + b1)  [8192x1024]
    gemm1_sk<<<256, 512, 0, stream>>>(xb, W1Tb, b1, hb);

    // 3. per-row: logits/mse/margin/zy/correct + v
    rows_kernel<<<NB / 4, 256, 0, stream>>>(hb, y, W2, b2, vb, rowstats);

    // 4. GEMM2: g = v @ W1^T, row |.| partials  [8192x2048]
    gemm2_v3<<<256, 512, 0, stream>>>(vb, W1b, part);

    // 5. reductions
    reduce_rows<<<NB / 256, 256, 0, stream>>>(rowstats, part, NL / 256, bsums);
    final_combine<<<1, 64, 0, stream>>>(bsums, NB / 256, out);
}

// Round 8
// 142.590 us; speedup vs baseline: 1.2014x; 1.2014x over previous
//
#include <hip/hip_runtime.h>
#include <hip/hip_bf16.h>

typedef unsigned short ushort_t;
typedef __attribute__((ext_vector_type(8))) short short8;
typedef __attribute__((ext_vector_type(8))) unsigned short u16x8;
typedef __attribute__((ext_vector_type(4))) float f32x4;

#define BETA 0.4f
#define EPS_C 0.05f
#define NB 8192
#define NH 1024
#define NL 2048
#define NC 5

static __device__ __forceinline__ float b2f(unsigned short u) {
    union { unsigned int i; float f; } x; x.i = ((unsigned int)u) << 16; return x.f;
}
static __device__ __forceinline__ unsigned short f2b(float f) {
    union { float f; unsigned int i; } x; x.f = f;
    unsigned int i = x.i;
    unsigned int r = (i + 0x7FFFu + ((i >> 16) & 1u)) >> 16;
    return (unsigned short)r;
}

static __device__ __forceinline__ void gload16(const ushort_t* g, ushort_t* l) {
    __builtin_amdgcn_global_load_lds((const __attribute__((address_space(1))) void*)g,
                                     (__attribute__((address_space(3))) void*)l, 16, 0, 0);
}

#define CFENCE() asm volatile("" ::: "memory")
#define MFMA16(d, a, b) __builtin_amdgcn_mfma_f32_16x16x32_bf16(a, b, d, 0, 0, 0)

// ---------------- conversion kernels ----------------
__global__ __launch_bounds__(256) void cvt_kernel(const float* __restrict__ in,
                                                  ushort_t* __restrict__ out, long n) {
    long i = ((long)blockIdx.x * 256 + threadIdx.x) * 8;
    if (i >= n) return;
    const float4 a = *(const float4*)(in + i);
    const float4 b = *(const float4*)(in + i + 4);
    u16x8 o;
    o[0] = f2b(a.x); o[1] = f2b(a.y); o[2] = f2b(a.z); o[3] = f2b(a.w);
    o[4] = f2b(b.x); o[5] = f2b(b.y); o[6] = f2b(b.z); o[7] = f2b(b.w);
    *(u16x8*)(out + i) = o;
}

// W1 [2048,1024] -> W1Tb [1024,2048] AND W1b [2048,1024] (fused cast)
__global__ __launch_bounds__(256) void trans_kernel(const float* __restrict__ W1,
                                                    ushort_t* __restrict__ W1Tb,
                                                    ushort_t* __restrict__ W1b) {
    __shared__ float tile[32][33];
    const int tx = threadIdx.x & 31, ty = threadIdx.x >> 5;
    const int k0 = blockIdx.x * 32, n0 = blockIdx.y * 32;
#pragma unroll
    for (int i = 0; i < 4; ++i) {
        const float v = W1[(size_t)(k0 + ty + i * 8) * NH + n0 + tx];
        tile[ty + i * 8][tx] = v;
        W1b[(size_t)(k0 + ty + i * 8) * NH + n0 + tx] = f2b(v);
    }
    __syncthreads();
#pragma unroll
    for (int i = 0; i < 4; ++i)
        W1Tb[(size_t)(n0 + ty + i * 8) * NL + k0 + tx] = f2b(tile[tx][ty + i * 8]);
}

// ---------------- GEMM1: round-3 proven structure (gemm8p<0>) ----------------
template <int EPI>
__global__ __launch_bounds__(512, 2) void gemm8p(const ushort_t* __restrict__ A,
                                                 const ushort_t* __restrict__ Bt,
                                                 const float* __restrict__ b1,
                                                 ushort_t* __restrict__ hout,
                                                 float* __restrict__ partout) {
    constexpr int BN_T = (EPI == 0) ? 128 : 256;
    constexpr int K    = (EPI == 0) ? 2048 : 1024;
    constexpr int NOUT = (EPI == 0) ? 1024 : 2048;
    constexpr int NT   = K / 64;
    constexpr int NPH  = (EPI == 0) ? 2 : 4;
    constexpr int MPP  = 8 / NPH;
    constexpr int NREP = BN_T / 64;

    __shared__ ushort_t As[2][16384];
    __shared__ ushort_t Bs[2][BN_T * 64];

    const int tid = threadIdx.x;
    const int wv = tid >> 6, lane = tid & 63;
    const int wm = wv >> 2, wn = wv & 3;
    const int fr = lane & 15, fg = lane >> 4;
    const int swz = (lane & 7) << 4;
    const int cbb = fg << 4;

    const int xcd = blockIdx.x & 7, loc = blockIdx.x >> 3;
    const int bm0 = (xcd * 4 + (loc >> 3)) * 256;
    const int bnIdx = loc & 7;
    const int bn0 = bnIdx * BN_T;

    const int srow = lane >> 3;
    const int scol = ((lane & 7) ^ srow) << 3;

    auto stA = [&](int buf, int kt, int half) {
#pragma unroll
        for (int c = 0; c < 2; ++c) {
            const int row = wv * 16 + c * 8 + srow;
            gload16(A + (size_t)(bm0 + half * 128 + row) * K + kt * 64 + scol,
                    &As[buf][half * 8192 + wv * 1024 + c * 512]);
        }
    };
    auto stB = [&](int buf, int kt, int half) {
#pragma unroll
        for (int c = 0; c < 2; ++c) {
            const int row = wv * 16 + c * 8 + srow;
            gload16(Bt + (size_t)(bn0 + half * 128 + row) * K + kt * 64 + scol,
                    &Bs[buf][half * 8192 + wv * 1024 + c * 512]);
        }
    };
    auto ldA = [&](int buf, int mf, int ks) -> short8 {
        const int rowt = wm * 128 + mf * 16 + fr;
        return *(const short8*)((const char*)&As[buf][0] + rowt * 128 + (((ks << 6) + cbb) ^ swz));
    };
    auto ldB = [&](int buf, int nf, int ks) -> short8 {
        const int rowt = wn * (BN_T / 4) + nf * 16 + fr;
        return *(const short8*)((const char*)&Bs[buf][0] + rowt * 128 + (((ks << 6) + cbb) ^ swz));
    };

    f32x4 acc[8][NREP] = {};

    stA(0, 0, 0); stA(0, 0, 1);
    stB(0, 0, 0);
    if constexpr (EPI == 1) stB(0, 0, 1);
    asm volatile("s_waitcnt vmcnt(0)" ::: "memory");
    CFENCE(); __builtin_amdgcn_s_barrier(); CFENCE();

#define TILEBODY(BUF, TT)                                                          \
    {                                                                              \
        const int ttv = (TT);                                                      \
        const bool more = ttv + 1 < NT;                                            \
        short8 bfl[NREP][2];                                                       \
        _Pragma("unroll")                                                          \
        for (int n = 0; n < NREP; ++n) {                                           \
            bfl[n][0] = ldB(BUF, n, 0);                                            \
            bfl[n][1] = ldB(BUF, n, 1);                                            \
        }                                                                          \
        _Pragma("unroll")                                                          \
        for (int p = 0; p < NPH; ++p) {                                            \
            short8 af[MPP][2];                                                     \
            _Pragma("unroll")                                                      \
            for (int i = 0; i < MPP; ++i) {                                        \
                af[i][0] = ldA(BUF, p * MPP + i, 0);                               \
                af[i][1] = ldA(BUF, p * MPP + i, 1);                               \
            }                                                                      \
            if (p == 0 && more) {                                                  \
                stA(BUF ^ 1, ttv + 1, 0);                                          \
                stA(BUF ^ 1, ttv + 1, 1);                                          \
                if constexpr (EPI == 0) stB(BUF ^ 1, ttv + 1, 0);                  \
            }                                                                      \
            if constexpr (EPI == 1)                                                \
                if (p == 1 && more) {                                              \
                    stB(BUF ^ 1, ttv + 1, 0);                                      \
                    stB(BUF ^ 1, ttv + 1, 1);                                      \
                }                                                                  \
            CFENCE(); __builtin_amdgcn_s_barrier(); CFENCE();                      \
            __builtin_amdgcn_s_setprio(1);                                         \
            _Pragma("unroll")                                                      \
            for (int i = 0; i < MPP; ++i) {                                        \
                _Pragma("unroll")                                                  \
                for (int n = 0; n < NREP; ++n) {                                   \
                    acc[p * MPP + i][n] = __builtin_amdgcn_mfma_f32_16x16x32_bf16( \
                        af[i][0], bfl[n][0], acc[p * MPP + i][n], 0, 0, 0);        \
                    acc[p * MPP + i][n] = __builtin_amdgcn_mfma_f32_16x16x32_bf16( \
                        af[i][1], bfl[n][1], acc[p * MPP + i][n], 0, 0, 0);        \
                }                                                                  \
            }                                                                      \
            __builtin_amdgcn_s_setprio(0);                                         \
            if (p == NPH - 1) asm volatile("s_waitcnt vmcnt(0)" ::: "memory");     \
            CFENCE(); __builtin_amdgcn_s_barrier(); CFENCE();                      \
        }                                                                          \
    }

#pragma unroll 1
    for (int t = 0; t < NT; t += 2) {
        TILEBODY(0, t)
        TILEBODY(1, t + 1)
    }
#undef TILEBODY

    if constexpr (EPI == 0) {
#pragma unroll
        for (int m = 0; m < 8; ++m)
#pragma unroll
            for (int n = 0; n < NREP; ++n) {
                const int col = bn0 + wn * 32 + n * 16 + fr;
                const float bb = b1[col];
                const size_t rbase = (size_t)(bm0 + wm * 128 + m * 16 + fg * 4) * NOUT + col;
#pragma unroll
                for (int r = 0; r < 4; ++r)
                    hout[rbase + (size_t)r * NOUT] = f2b(tanhf(acc[m][n][r] + bb));
            }
    } else {
        float* rsum = (float*)&As[0][0];
#pragma unroll
        for (int m = 0; m < 8; ++m)
#pragma unroll
            for (int r = 0; r < 4; ++r) {
                float s = 0.f;
#pragma unroll
                for (int n = 0; n < NREP; ++n) s += fabsf(acc[m][n][r]);
                s += __shfl_xor(s, 1); s += __shfl_xor(s, 2);
                s += __shfl_xor(s, 4); s += __shfl_xor(s, 8);
                if (fr == 0) rsum[wn * 256 + wm * 128 + m * 16 + fg * 4 + r] = s;
            }
        __syncthreads();
        if (tid < 256)
            partout[(size_t)bnIdx * NB + bm0 + tid] =
                rsum[tid] + rsum[256 + tid] + rsum[512 + tid] + rsum[768 + tid];
    }
}

// ============ GEMM2: m201-style counted-vmcnt ring (k-half staging groups) ============
// A=v [8192,1024], Bt=W1b [2048,1024]; tile 256x256, BK=64, NT=16.
// Buf layout per matrix: [2 kh][128 pair-rows][8 slots x 8 elems]; slot sl holds
// logical ((row&1)<<2 | kchunk) ^ (r1&7)  -> 2-way bank aliasing (free).
// Stage groups: G(t,kh) = {A-khalf (2 loads) + B-khalf (2 loads)}.
// Schedule/tile: p1[rd kh0 a+b01; stage G(t+1,0)] p2[rd b23; stage G(t+1,1); vmcnt(8)]
//                p3[rd kh1 a+b01] p4[rd b23; vmcnt(4)]  -- queue never empty.
__global__ __launch_bounds__(512, 2) void gemm2_m201(const ushort_t* __restrict__ A,
                                                     const ushort_t* __restrict__ Bt,
                                                     float* __restrict__ partout) {
    constexpr int NT = 16;
    __shared__ ushort_t As[2][16384];
    __shared__ ushort_t Bs[2][16384];

    const int tid = threadIdx.x;
    const int wv = tid >> 6, lane = tid & 63;
    const int wm = wv >> 2, wn = wv & 3;       // wave tile 128(M) x 64(N)
    const int fr = lane & 15, fg = lane >> 4;
    const int xcd = blockIdx.x & 7, loc = blockIdx.x >> 3;
    const int bm0 = (xcd * 4 + (loc >> 3)) * 256;
    const int bnIdx = loc & 7;
    const int bn0 = bnIdx * 256;

    // staging source math (per lane): r1 = pair-row, sl = phys slot -> logical
    const int l8 = lane >> 3, l7 = lane & 7;

#define STA(BUFN, KH, KT) {                                                        \
    _Pragma("unroll") for (int j = 0; j < 2; ++j) {                                \
        const int r1_ = j * 64 + wv * 8 + l8;                                      \
        const int sl_ = l7 ^ (r1_ & 7);                                            \
        const int row_ = 2 * r1_ + (sl_ >> 2);                                     \
        const int kc_ = (KT) * 64 + (KH) * 32 + (sl_ & 3) * 8;                     \
        gload16(A + (size_t)(bm0 + row_) * 1024 + kc_,                             \
                &As[BUFN][(KH) * 8192 + j * 4096 + wv * 512]);                     \
    } }
#define STB(BUFN, KH, KT) {                                                        \
    _Pragma("unroll") for (int j = 0; j < 2; ++j) {                                \
        const int r1_ = j * 64 + wv * 8 + l8;                                      \
        const int sl_ = l7 ^ (r1_ & 7);                                            \
        const int row_ = 2 * r1_ + (sl_ >> 2);                                     \
        const int kc_ = (KT) * 64 + (KH) * 32 + (sl_ & 3) * 8;                     \
        gload16(Bt + (size_t)(bn0 + row_) * 1024 + kc_,                            \
                &Bs[BUFN][(KH) * 8192 + j * 4096 + wv * 512]);                     \
    } }

    auto ldA = [&](int buf, int kh, int mf) -> short8 {
        const int row = wm * 128 + mf * 16 + fr;
        const int r1 = row >> 1;
        const int sl = (((row & 1) << 2) | fg) ^ (r1 & 7);
        return *(const short8*)&As[buf][kh * 8192 + r1 * 64 + sl * 8];
    };
    auto ldB = [&](int buf, int kh, int nf) -> short8 {
        const int row = wn * 64 + nf * 16 + fr;
        const int r1 = row >> 1;
        const int sl = (((row & 1) << 2) | fg) ^ (r1 & 7);
        return *(const short8*)&Bs[buf][kh * 8192 + r1 * 64 + sl * 8];
    };

    f32x4 acc[8][4] = {};

    // prologue: stage G(0,0), G(0,1); counted wait for G(0,0); barrier
    STA(0, 0, 0) STB(0, 0, 0)
    STA(0, 1, 0) STB(0, 1, 0)
    asm volatile("s_waitcnt vmcnt(4)" ::: "memory");
    CFENCE(); __builtin_amdgcn_s_barrier(); CFENCE();

#define BARPAIR_MFMA(NLO, NHI, AFARR, BARR)                                        \
    CFENCE(); __builtin_amdgcn_s_barrier(); CFENCE();                              \
    __builtin_amdgcn_s_setprio(1);                                                 \
    _Pragma("unroll") for (int m = 0; m < 8; ++m) {                                \
        acc[m][NLO] = MFMA16(acc[m][NLO], AFARR[m], BARR[0]);                      \
        acc[m][NHI] = MFMA16(acc[m][NHI], AFARR[m], BARR[1]);                      \
    }                                                                              \
    __builtin_amdgcn_s_setprio(0);                                                 \
    CFENCE(); __builtin_amdgcn_s_barrier(); CFENCE();

#define G2TILE(BUF, NXT, TT) {                                                     \
    const int t_ = (TT);                                                           \
    const bool more = (t_ + 1 < NT);                                               \
    short8 af[8], bA[2], bB[2];                                                    \
    /* p1: reads kh0 A + B n01; stage G(t+1,0) */                                  \
    _Pragma("unroll") for (int m = 0; m < 8; ++m) af[m] = ldA(BUF, 0, m);          \
    bA[0] = ldB(BUF, 0, 0); bA[1] = ldB(BUF, 0, 1);                                \
    if (more) { STA(NXT, 0, t_ + 1) STB(NXT, 0, t_ + 1) }                          \
    BARPAIR_MFMA(0, 1, af, bA)                                                     \
    /* p2: reads B n23; stage G(t+1,1); vmcnt(8) ensures G(t,1) landed */          \
    bB[0] = ldB(BUF, 0, 2); bB[1] = ldB(BUF, 0, 3);                                \
    if (more) {                                                                    \
        STA(NXT, 1, t_ + 1) STB(NXT, 1, t_ + 1)                                    \
        asm volatile("s_waitcnt vmcnt(8)" ::: "memory");                           \
    } else {                                                                       \
        asm volatile("s_waitcnt vmcnt(0)" ::: "memory");                           \
    }                                                                              \
    BARPAIR_MFMA(2, 3, af, bB)                                                     \
    /* p3: reads kh1 A + B n01 */                                                  \
    _Pragma("unroll") for (int m = 0; m < 8; ++m) af[m] = ldA(BUF, 1, m);          \
    bA[0] = ldB(BUF, 1, 0); bA[1] = ldB(BUF, 1, 1);                                \
    BARPAIR_MFMA(0, 1, af, bA)                                                     \
    /* p4: reads B n23; vmcnt(4) ensures G(t+1,0) landed */                        \
    bB[0] = ldB(BUF, 1, 2); bB[1] = ldB(BUF, 1, 3);                                \
    if (more) { asm volatile("s_waitcnt vmcnt(4)" ::: "memory"); }                 \
    else      { asm volatile("s_waitcnt vmcnt(0)" ::: "memory"); }                 \
    BARPAIR_MFMA(2, 3, af, bB)                                                     \
    }

#pragma unroll 1
    for (int t = 0; t < NT; t += 2) {
        G2TILE(0, 1, t)
        G2TILE(1, 0, t + 1)
    }
#undef G2TILE
#undef BARPAIR_MFMA
#undef STA
#undef STB

    // epilogue: per-row |.| partial sums (proven pattern)
    __syncthreads();
    float* rsum = (float*)&As[0][0];
#pragma unroll
    for (int m = 0; m < 8; ++m)
#pragma unroll
        for (int r = 0; r < 4; ++r) {
            float s = 0.f;
#pragma unroll
            for (int n = 0; n < 4; ++n) s += fabsf(acc[m][n][r]);
            s += __shfl_xor(s, 1); s += __shfl_xor(s, 2);
            s += __shfl_xor(s, 4); s += __shfl_xor(s, 8);
            if (fr == 0) rsum[wn * 256 + wm * 128 + m * 16 + fg * 4 + r] = s;
        }
    __syncthreads();
    if (tid < 256)
        partout[(size_t)bnIdx * NB + bm0 + tid] =
            rsum[tid] + rsum[256 + tid] + rsum[512 + tid] + rsum[768 + tid];
}

// ---------------- per-row kernel: logits, losses, v ----------------
__global__ __launch_bounds__(256) void rows_kernel(const ushort_t* __restrict__ hb,
                                                   const int* __restrict__ y,
                                                   const float* __restrict__ W2,
                                                   const float* __restrict__ b2,
                                                   ushort_t* __restrict__ vb,
                                                   float4* __restrict__ rowstats) {
    __shared__ float w2s[NH * NC];
    __shared__ float b2s[NC];
    const int tid = threadIdx.x;
    for (int i = tid; i < NH * NC; i += 256) w2s[i] = W2[i];
    if (tid < NC) b2s[tid] = b2[tid];
    __syncthreads();
    const int wid = tid >> 6, lane = tid & 63;
    const int row = blockIdx.x * 4 + wid;
    const ushort_t* hrow = hb + (size_t)row * NH;
    ushort_t* vrow = vb + (size_t)row * NH;
    const int yi = y[row];
    float d0 = 0, d1 = 0, d2 = 0, d3 = 0, d4 = 0;
#pragma unroll
    for (int it = 0; it < 2; ++it) {
        const int n0 = it * 512 + lane * 8;
        u16x8 hv = *(const u16x8*)(hrow + n0);
        u16x8 ov;
#pragma unroll
        for (int j = 0; j < 8; ++j) {
            float hh = b2f(hv[j]);
            const float* wrow = &w2s[(n0 + j) * NC];
            d0 += hh * wrow[0]; d1 += hh * wrow[1]; d2 += hh * wrow[2];
            d3 += hh * wrow[3]; d4 += hh * wrow[4];
            ov[j] = f2b((1.f - hh * hh) * wrow[yi]);
        }
        *(u16x8*)(vrow + n0) = ov;
    }
#pragma unroll
    for (int off = 32; off; off >>= 1) {
        d0 += __shfl_xor(d0, off); d1 += __shfl_xor(d1, off); d2 += __shfl_xor(d2, off);
        d3 += __shfl_xor(d3, off); d4 += __shfl_xor(d4, off);
    }
    if (lane == 0) {
        float lg[NC] = { d0 + b2s[0], d1 + b2s[1], d2 + b2s[2], d3 + b2s[3], d4 + b2s[4] };
        float zy = lg[yi];
        float mse = 0.f, marg = 0.f;
        int amax = 0; float best = lg[0];
#pragma unroll
        for (int c = 0; c < NC; ++c) {
            float t = lg[c] - (c == yi ? 1.f : 0.f);
            mse += t * t;
            if (c != yi) marg += fmaxf(1.f - zy + lg[c], 0.f);
            if (lg[c] > best) { best = lg[c]; amax = c; }
        }
        rowstats[row] = make_float4(zy, mse, marg, (amax == yi) ? 1.f : 0.f);
    }
}

// ---------------- reductions ----------------
__global__ __launch_bounds__(256) void reduce_rows(const float4* __restrict__ rs,
                                                   const float* __restrict__ part,
                                                   int NT, float4* __restrict__ bsums) {
    const int tid = threadIdx.x;
    const int r = blockIdx.x * 256 + tid;
    float4 v = rs[r];
    float wl1 = 0.f;
    for (int t = 0; t < NT; ++t) wl1 += part[(size_t)t * NB + r];
    float R = wl1 * EPS_C / (fabsf(v.x) + 1e-8f);
    float4 s = make_float4(v.y, v.z, v.w, log1pf(R));
#pragma unroll
    for (int off = 32; off; off >>= 1) {
        s.x += __shfl_down(s.x, off); s.y += __shfl_down(s.y, off);
        s.z += __shfl_down(s.z, off); s.w += __shfl_down(s.w, off);
    }
    __shared__ float4 red[4];
    if ((tid & 63) == 0) red[tid >> 6] = s;
    __syncthreads();
    if (tid == 0) {
        float4 t = red[0];
        for (int i = 1; i < 4; ++i) { t.x += red[i].x; t.y += red[i].y; t.z += red[i].z; t.w += red[i].w; }
        bsums[blockIdx.x] = t;
    }
}

__global__ void final_combine(const float4* __restrict__ bsums, int nb, float* __restrict__ out) {
    const int l = threadIdx.x;
    float4 s = (l < nb) ? bsums[l] : make_float4(0.f, 0.f, 0.f, 0.f);
#pragma unroll
    for (int off = 32; off; off >>= 1) {
        s.x += __shfl_down(s.x, off); s.y += __shfl_down(s.y, off);
        s.z += __shfl_down(s.z, off); s.w += __shfl_down(s.w, off);
    }
    if (l == 0) {
        const float Bf = (float)NB;
        out[0] = s.x / (Bf * (float)NC) + (s.y / Bf + BETA * s.w / Bf) * (s.z / Bf);
    }
}

extern "C" void kernel_launch(void* const* d_in, const int* in_sizes, int n_in,
                              void* d_out, int out_size, void* d_ws, size_t ws_size,
                              hipStream_t stream) {
    const float* x  = (const float*)d_in[0];
    const int*   y  = (const int*)d_in[1];
    const float* W1 = (const float*)d_in[2];
    const float* b1 = (const float*)d_in[3];
    const float* W2 = (const float*)d_in[4];
    const float* b2 = (const float*)d_in[5];
    float* out = (float*)d_out;

    char* ws = (char*)d_ws;
    ushort_t* W1Tb = (ushort_t*)(ws);                           // 4MB
    ushort_t* W1b  = (ushort_t*)(ws + (4ul << 20));             // 4MB
    ushort_t* xb   = (ushort_t*)(ws + (8ul << 20));             // 32MB
    ushort_t* hb   = (ushort_t*)(ws + (40ul << 20));            // 16MB
    ushort_t* vb   = (ushort_t*)(ws + (56ul << 20));            // 16MB
    float4*   rowstats = (float4*)(ws + (72ul << 20));          // 128KB
    float*    part = (float*)(ws + (72ul << 20) + (1ul << 20)); // 256KB
    float4*   bsums = (float4*)(ws + (74ul << 20));             // 512B

    // 1. conversions (W1 cast fused into transpose kernel)
    cvt_kernel<<<(NB * (long)NL) / (256 * 8), 256, 0, stream>>>(x, xb, (long)NB * NL);
    trans_kernel<<<dim3(NL / 32, NH / 32), 256, 0, stream>>>(W1, W1Tb, W1b);

    // 2. GEMM1 (proven): h = tanh(x @ W1 + b1)  [8192x1024]
    gemm8p<0><<<256, 512, 0, stream>>>(xb, W1Tb, b1, hb, nullptr);

    // 3. per-row: logits/mse/margin/zy/correct + v
    rows_kernel<<<NB / 4, 256, 0, stream>>>(hb, y, W2, b2, vb, rowstats);

    // 4. GEMM2 (m201 counted-vmcnt ring): g = v @ W1^T, row |.| partials
    gemm2_m201<<<256, 512, 0, stream>>>(vb, W1b, part);

    // 5. reductions
    reduce_rows<<<NB / 256, 256, 0, stream>>>(rowstats, part, NL / 256, bsums);
    final_combine<<<1, 64, 0, stream>>>(bsums, NB / 256, out);
}

// Round 9
// 123.859 us; speedup vs baseline: 1.3830x; 1.1512x over previous
//
#include <hip/hip_runtime.h>
#include <hip/hip_bf16.h>

typedef unsigned short ushort_t;
typedef __attribute__((ext_vector_type(8))) short short8;
typedef __attribute__((ext_vector_type(8))) unsigned short u16x8;
typedef __attribute__((ext_vector_type(4))) float f32x4;

#define BETA 0.4f
#define EPS_C 0.05f
#define NB 8192
#define NH 1024
#define NL 2048
#define NC 5

static __device__ __forceinline__ float b2f(unsigned short u) {
    union { unsigned int i; float f; } x; x.i = ((unsigned int)u) << 16; return x.f;
}
static __device__ __forceinline__ unsigned short f2b(float f) {
    union { float f; unsigned int i; } x; x.f = f;
    unsigned int i = x.i;
    unsigned int r = (i + 0x7FFFu + ((i >> 16) & 1u)) >> 16;
    return (unsigned short)r;
}

static __device__ __forceinline__ void gload16(const ushort_t* g, ushort_t* l) {
    __builtin_amdgcn_global_load_lds((const __attribute__((address_space(1))) void*)g,
                                     (__attribute__((address_space(3))) void*)l, 16, 0, 0);
}

#define CFENCE() asm volatile("" ::: "memory")
#define MFMA16(d, a, b) __builtin_amdgcn_mfma_f32_16x16x32_bf16(a, b, d, 0, 0, 0)

// ---------------- conversion kernels ----------------
__global__ __launch_bounds__(256) void cvt_kernel(const float* __restrict__ in,
                                                  ushort_t* __restrict__ out, long n) {
    long i = ((long)blockIdx.x * 256 + threadIdx.x) * 8;
    if (i >= n) return;
    const float4 a = *(const float4*)(in + i);
    const float4 b = *(const float4*)(in + i + 4);
    u16x8 o;
    o[0] = f2b(a.x); o[1] = f2b(a.y); o[2] = f2b(a.z); o[3] = f2b(a.w);
    o[4] = f2b(b.x); o[5] = f2b(b.y); o[6] = f2b(b.z); o[7] = f2b(b.w);
    *(u16x8*)(out + i) = o;
}

// W1 [2048,1024] -> W1Tb [1024,2048] AND W1b [2048,1024] (fused cast)
__global__ __launch_bounds__(256) void trans_kernel(const float* __restrict__ W1,
                                                    ushort_t* __restrict__ W1Tb,
                                                    ushort_t* __restrict__ W1b) {
    __shared__ float tile[32][33];
    const int tx = threadIdx.x & 31, ty = threadIdx.x >> 5;
    const int k0 = blockIdx.x * 32, n0 = blockIdx.y * 32;
#pragma unroll
    for (int i = 0; i < 4; ++i) {
        const float v = W1[(size_t)(k0 + ty + i * 8) * NH + n0 + tx];
        tile[ty + i * 8][tx] = v;
        W1b[(size_t)(k0 + ty + i * 8) * NH + n0 + tx] = f2b(v);
    }
    __syncthreads();
#pragma unroll
    for (int i = 0; i < 4; ++i)
        W1Tb[(size_t)(n0 + ty + i * 8) * NL + k0 + tx] = f2b(tile[tx][ty + i * 8]);
}

// ============ 128x128 double-buffered GEMM, 2 blocks/CU (cross-block overlap) ============
// EPI 0: GEMM1  A=xb[8192,2048] Bt=W1Tb[1024,2048]  grid 512, tanh -> hout
// EPI 1: GEMM2  A=vb[8192,1024] Bt=W1b [2048,1024]  grid 1024, row |.| partials
template <int EPI>
__global__ __launch_bounds__(256, 2) void g128(const ushort_t* __restrict__ A,
                                               const ushort_t* __restrict__ Bt,
                                               const float* __restrict__ b1,
                                               ushort_t* __restrict__ hout,
                                               float* __restrict__ partout) {
    constexpr int K  = (EPI == 0) ? 2048 : 1024;
    constexpr int NT = K / 64;                     // 32 / 16 (even)
    constexpr int NPAN = (EPI == 0) ? 8 : 16;      // bn panels

    __shared__ ushort_t As[2][8192];   // 128 x 64, 128B rows, XOR-swz (32KB)
    __shared__ ushort_t Bs[2][8192];   // 128 x 64 (32KB)

    const int tid = threadIdx.x;
    const int wv = tid >> 6, lane = tid & 63;
    const int wm = (wv >> 1) & 1, wn = wv & 1;     // wave tile 64x64
    const int fr = lane & 15, fg = lane >> 4;

    const int xcd = blockIdx.x & 7, loc = blockIdx.x >> 3;
    const int bmLoc = (EPI == 0) ? (loc >> 3) : (loc >> 4);
    const int bnIdx = (EPI == 0) ? (loc & 7) : (loc & 15);
    const int bm0 = (xcd * 8 + bmLoc) * 128;
    const int bn0 = bnIdx * 128;

    const int srow = lane >> 3;
    const int scol = ((lane & 7) ^ srow) << 3;     // pre-swizzled source col

#define STA(BUF, KT) {                                                      \
    _Pragma("unroll") for (int c_ = 0; c_ < 4; ++c_) {                      \
        const int row_ = c_ * 32 + wv * 8 + srow;                           \
        gload16(A + (size_t)(bm0 + row_) * K + (KT) * 64 + scol,            \
                &As[BUF][c_ * 2048 + wv * 512]);                            \
    } }
#define STB(BUF, KT) {                                                      \
    _Pragma("unroll") for (int c_ = 0; c_ < 4; ++c_) {                      \
        const int row_ = c_ * 32 + wv * 8 + srow;                           \
        gload16(Bt + (size_t)(bn0 + row_) * K + (KT) * 64 + scol,           \
                &Bs[BUF][c_ * 2048 + wv * 512]);                            \
    } }

    auto ldA = [&](int buf, int mf, int ks) -> short8 {
        const int row = wm * 64 + mf * 16 + fr;
        const int slot = ((ks << 2) + fg) ^ (row & 7);
        return *(const short8*)&As[buf][row * 64 + slot * 8];
    };
    auto ldB = [&](int buf, int nf, int ks) -> short8 {
        const int row = wn * 64 + nf * 16 + fr;
        const int slot = ((ks << 2) + fg) ^ (row & 7);
        return *(const short8*)&Bs[buf][row * 64 + slot * 8];
    };

    f32x4 acc[4][4] = {};

    // prologue: stage tile 0 into buf0, drain, align
    STA(0, 0) STB(0, 0)
    asm volatile("s_waitcnt vmcnt(0)" ::: "memory");
    CFENCE(); __builtin_amdgcn_s_barrier(); CFENCE();

#define TILE(BUF, TT) {                                                     \
    const int t_ = (TT);                                                    \
    short8 af[4][2], bf[4][2];                                              \
    _Pragma("unroll") for (int n_ = 0; n_ < 4; ++n_) {                      \
        bf[n_][0] = ldB(BUF, n_, 0); bf[n_][1] = ldB(BUF, n_, 1);           \
    }                                                                       \
    _Pragma("unroll") for (int m_ = 0; m_ < 4; ++m_) {                      \
        af[m_][0] = ldA(BUF, m_, 0); af[m_][1] = ldA(BUF, m_, 1);           \
    }                                                                       \
    if (t_ + 1 < NT) { STA(BUF ^ 1, t_ + 1) STB(BUF ^ 1, t_ + 1) }          \
    CFENCE(); __builtin_amdgcn_s_barrier(); CFENCE();                       \
    __builtin_amdgcn_s_setprio(1);                                          \
    _Pragma("unroll") for (int m_ = 0; m_ < 4; ++m_)                        \
        _Pragma("unroll") for (int n_ = 0; n_ < 4; ++n_) {                  \
            acc[m_][n_] = MFMA16(acc[m_][n_], af[m_][0], bf[n_][0]);        \
            acc[m_][n_] = MFMA16(acc[m_][n_], af[m_][1], bf[n_][1]);        \
        }                                                                   \
    __builtin_amdgcn_s_setprio(0);                                          \
    asm volatile("s_waitcnt vmcnt(0)" ::: "memory");                        \
    CFENCE(); __builtin_amdgcn_s_barrier(); CFENCE();                       \
    }

#pragma unroll 1
    for (int t = 0; t < NT; t += 2) {
        TILE(0, t)
        TILE(1, t + 1)
    }
#undef TILE
#undef STA
#undef STB

    if constexpr (EPI == 0) {
#pragma unroll
        for (int m = 0; m < 4; ++m)
#pragma unroll
            for (int n = 0; n < 4; ++n) {
                const int col = bn0 + wn * 64 + n * 16 + fr;
                const float bb = b1[col];
                const size_t rbase = (size_t)(bm0 + wm * 64 + m * 16 + fg * 4) * NH + col;
#pragma unroll
                for (int r = 0; r < 4; ++r)
                    hout[rbase + (size_t)r * NH] = f2b(tanhf(acc[m][n][r] + bb));
            }
    } else {
        __syncthreads();
        float* rsum = (float*)&As[0][0];   // 2 x 128 floats
#pragma unroll
        for (int m = 0; m < 4; ++m)
#pragma unroll
            for (int r = 0; r < 4; ++r) {
                float s = 0.f;
#pragma unroll
                for (int n = 0; n < 4; ++n) s += fabsf(acc[m][n][r]);
                s += __shfl_xor(s, 1); s += __shfl_xor(s, 2);
                s += __shfl_xor(s, 4); s += __shfl_xor(s, 8);
                if (fr == 0) rsum[wn * 128 + wm * 64 + m * 16 + fg * 4 + r] = s;
            }
        __syncthreads();
        if (tid < 128)
            partout[(size_t)bnIdx * NB + bm0 + tid] = rsum[tid] + rsum[128 + tid];
    }
}

// ---------------- per-row kernel: logits, losses, v (transposed-W2 LDS) ----------------
__global__ __launch_bounds__(256) void rows_kernel(const ushort_t* __restrict__ hb,
                                                   const int* __restrict__ y,
                                                   const float* __restrict__ W2,
                                                   const float* __restrict__ b2,
                                                   ushort_t* __restrict__ vb,
                                                   float4* __restrict__ rowstats) {
    __shared__ float w2t[NC][NH];
    __shared__ float b2s[NC];
    const int tid = threadIdx.x;
    for (int i = tid; i < NH * NC; i += 256) w2t[i % NC][i / NC] = W2[i];
    if (tid < NC) b2s[tid] = b2[tid];
    __syncthreads();
    const int wid = tid >> 6, lane = tid & 63;
    const int row = blockIdx.x * 4 + wid;
    const ushort_t* hrow = hb + (size_t)row * NH;
    ushort_t* vrow = vb + (size_t)row * NH;
    const int yi = y[row];
    float d0 = 0, d1 = 0, d2 = 0, d3 = 0, d4 = 0;
#pragma unroll
    for (int it = 0; it < 2; ++it) {
        const int n0 = it * 512 + lane * 8;
        u16x8 hv = *(const u16x8*)(hrow + n0);
        float hh[8];
#pragma unroll
        for (int j = 0; j < 8; ++j) hh[j] = b2f(hv[j]);
#pragma unroll
        for (int c = 0; c < NC; ++c) {
            const float4 a = *(const float4*)&w2t[c][n0];
            const float4 b = *(const float4*)&w2t[c][n0 + 4];
            float d = hh[0] * a.x; d += hh[1] * a.y; d += hh[2] * a.z; d += hh[3] * a.w;
            d += hh[4] * b.x; d += hh[5] * b.y; d += hh[6] * b.z; d += hh[7] * b.w;
            if (c == 0) d0 += d; else if (c == 1) d1 += d; else if (c == 2) d2 += d;
            else if (c == 3) d3 += d; else d4 += d;
        }
        const float4 ya = *(const float4*)&w2t[yi][n0];
        const float4 yb = *(const float4*)&w2t[yi][n0 + 4];
        const float yw[8] = { ya.x, ya.y, ya.z, ya.w, yb.x, yb.y, yb.z, yb.w };
        u16x8 ov;
#pragma unroll
        for (int j = 0; j < 8; ++j)
            ov[j] = f2b((1.f - hh[j] * hh[j]) * yw[j]);
        *(u16x8*)(vrow + n0) = ov;
    }
#pragma unroll
    for (int off = 32; off; off >>= 1) {
        d0 += __shfl_xor(d0, off); d1 += __shfl_xor(d1, off); d2 += __shfl_xor(d2, off);
        d3 += __shfl_xor(d3, off); d4 += __shfl_xor(d4, off);
    }
    if (lane == 0) {
        float lg[NC] = { d0 + b2s[0], d1 + b2s[1], d2 + b2s[2], d3 + b2s[3], d4 + b2s[4] };
        float zy = lg[yi];
        float mse = 0.f, marg = 0.f;
        int amax = 0; float best = lg[0];
#pragma unroll
        for (int c = 0; c < NC; ++c) {
            float t = lg[c] - (c == yi ? 1.f : 0.f);
            mse += t * t;
            if (c != yi) marg += fmaxf(1.f - zy + lg[c], 0.f);
            if (lg[c] > best) { best = lg[c]; amax = c; }
        }
        rowstats[row] = make_float4(zy, mse, marg, (amax == yi) ? 1.f : 0.f);
    }
}

// ---------------- reductions ----------------
__global__ __launch_bounds__(256) void reduce_rows(const float4* __restrict__ rs,
                                                   const float* __restrict__ part,
                                                   int NT, float4* __restrict__ bsums) {
    const int tid = threadIdx.x;
    const int r = blockIdx.x * 256 + tid;
    float4 v = rs[r];
    float wl1 = 0.f;
    for (int t = 0; t < NT; ++t) wl1 += part[(size_t)t * NB + r];
    float R = wl1 * EPS_C / (fabsf(v.x) + 1e-8f);
    float4 s = make_float4(v.y, v.z, v.w, log1pf(R));
#pragma unroll
    for (int off = 32; off; off >>= 1) {
        s.x += __shfl_down(s.x, off); s.y += __shfl_down(s.y, off);
        s.z += __shfl_down(s.z, off); s.w += __shfl_down(s.w, off);
    }
    __shared__ float4 red[4];
    if ((tid & 63) == 0) red[tid >> 6] = s;
    __syncthreads();
    if (tid == 0) {
        float4 t = red[0];
        for (int i = 1; i < 4; ++i) { t.x += red[i].x; t.y += red[i].y; t.z += red[i].z; t.w += red[i].w; }
        bsums[blockIdx.x] = t;
    }
}

__global__ void final_combine(const float4* __restrict__ bsums, int nb, float* __restrict__ out) {
    const int l = threadIdx.x;
    float4 s = (l < nb) ? bsums[l] : make_float4(0.f, 0.f, 0.f, 0.f);
#pragma unroll
    for (int off = 32; off; off >>= 1) {
        s.x += __shfl_down(s.x, off); s.y += __shfl_down(s.y, off);
        s.z += __shfl_down(s.z, off); s.w += __shfl_down(s.w, off);
    }
    if (l == 0) {
        const float Bf = (float)NB;
        out[0] = s.x / (Bf * (float)NC) + (s.y / Bf + BETA * s.w / Bf) * (s.z / Bf);
    }
}

extern "C" void kernel_launch(void* const* d_in, const int* in_sizes, int n_in,
                              void* d_out, int out_size, void* d_ws, size_t ws_size,
                              hipStream_t stream) {
    const float* x  = (const float*)d_in[0];
    const int*   y  = (const int*)d_in[1];
    const float* W1 = (const float*)d_in[2];
    const float* b1 = (const float*)d_in[3];
    const float* W2 = (const float*)d_in[4];
    const float* b2 = (const float*)d_in[5];
    float* out = (float*)d_out;

    char* ws = (char*)d_ws;
    ushort_t* W1Tb = (ushort_t*)(ws);                           // 4MB
    ushort_t* W1b  = (ushort_t*)(ws + (4ul << 20));             // 4MB
    ushort_t* xb   = (ushort_t*)(ws + (8ul << 20));             // 32MB
    ushort_t* hb   = (ushort_t*)(ws + (40ul << 20));            // 16MB
    ushort_t* vb   = (ushort_t*)(ws + (56ul << 20));            // 16MB
    float4*   rowstats = (float4*)(ws + (72ul << 20));          // 128KB
    float*    part = (float*)(ws + (72ul << 20) + (1ul << 20)); // 512KB (16 x 8192 f32)
    float4*   bsums = (float4*)(ws + (74ul << 20));             // 512B

    // 1. conversions (W1 cast fused into transpose kernel)
    cvt_kernel<<<(NB * (long)NL) / (256 * 8), 256, 0, stream>>>(x, xb, (long)NB * NL);
    trans_kernel<<<dim3(NL / 32, NH / 32), 256, 0, stream>>>(W1, W1Tb, W1b);

    // 2. GEMM1 (128^2, 2 blocks/CU): h = tanh(x @ W1 + b1)
    g128<0><<<512, 256, 0, stream>>>(xb, W1Tb, b1, hb, nullptr);

    // 3. per-row: logits/mse/margin/zy/correct + v
    rows_kernel<<<NB / 4, 256, 0, stream>>>(hb, y, W2, b2, vb, rowstats);

    // 4. GEMM2 (128^2, 2 blocks/CU): g = v @ W1^T, row |.| partials
    g128<1><<<1024, 256, 0, stream>>>(vb, W1b, nullptr, nullptr, part);

    // 5. reductions
    reduce_rows<<<NB / 256, 256, 0, stream>>>(rowstats, part, NL / 128, bsums);
    final_combine<<<1, 64, 0, stream>>>(bsums, NB / 256, out);
}